// Round 1
// baseline (539.411 us; speedup 1.0000x reference)
//
#include <hip/hip_runtime.h>
#include <math.h>

#define B_   32
#define S_   4
#define H_   16
#define D_   64
#define E_   1024
#define KV_  4096
#define NBH  512            // B_*H_
#define CS   512            // cached rows per chunk
#define NC   9              // 8 cache chunks + 1 "new rows" chunk
#define RECSZ 264           // 4 m + 4 l + 256 O floats per partial record

// ---------------------------------------------------------------------------
// Small GEMM: out = A[128,1024] @ W[1024,1024]^T + bias
// mode 0: scatter to [b,h,s,d] (for Q/K/V projections)
// mode 1: linear [t][e]        (for the output projection)
// grid (32, 16), block 256
// ---------------------------------------------------------------------------
__global__ __launch_bounds__(256) void proj_kernel(
    const float* __restrict__ A, const float* __restrict__ W,
    const float* __restrict__ bias, float* __restrict__ out, int mode) {
    __shared__ float a_lds[4 * E_];
    const int t0 = blockIdx.x * 4;
    const int n0 = blockIdx.y * 64;
    const int tid = threadIdx.x;

    const float4* Ag = (const float4*)(A + (size_t)t0 * E_);
    float4* al = (float4*)a_lds;
    #pragma unroll
    for (int i = 0; i < 4; ++i) al[tid + 256 * i] = Ag[tid + 256 * i];
    __syncthreads();

    const int tx = tid & 63, ty = tid >> 6;
    const float4* ar = (const float4*)(a_lds + ty * E_);
    const float4* wr = (const float4*)(W + (size_t)(n0 + tx) * E_);
    float acc = 0.f;
    #pragma unroll 8
    for (int k = 0; k < E_ / 4; ++k) {
        float4 a = ar[k], w = wr[k];
        acc = fmaf(a.x, w.x, acc);
        acc = fmaf(a.y, w.y, acc);
        acc = fmaf(a.z, w.z, acc);
        acc = fmaf(a.w, w.w, acc);
    }
    acc += bias[n0 + tx];
    const int t = t0 + ty, e = n0 + tx;
    if (mode == 0) {
        const int b = t >> 2, s = t & 3, h = e >> 6, dk = e & 63;
        out[((size_t)((b * H_ + h) * S_ + s)) * D_ + dk] = acc;
    } else {
        out[(size_t)t * E_ + e] = acc;
    }
}

// ---------------------------------------------------------------------------
// Attention partials (flash-decoding)
// ---------------------------------------------------------------------------
__device__ __forceinline__ float4 score4(const float4* __restrict__ q4,
                                         const float* __restrict__ kptr, int r) {
    const float4* krow = (const float4*)(kptr + (size_t)r * D_);
    float sx = 0.f, sy = 0.f, sz = 0.f, sw = 0.f;
    #pragma unroll
    for (int k = 0; k < 16; ++k) {
        float4 kv = krow[k];
        float4 q0 = q4[k];
        float4 q1 = q4[16 + k];
        float4 q2 = q4[32 + k];
        float4 q3 = q4[48 + k];
        sx += kv.x * q0.x + kv.y * q0.y + kv.z * q0.z + kv.w * q0.w;
        sy += kv.x * q1.x + kv.y * q1.y + kv.z * q1.z + kv.w * q1.w;
        sz += kv.x * q2.x + kv.y * q2.y + kv.z * q2.z + kv.w * q2.w;
        sw += kv.x * q3.x + kv.y * q3.y + kv.z * q3.z + kv.w * q3.w;
    }
    return make_float4(sx * 0.125f, sy * 0.125f, sz * 0.125f, sw * 0.125f);
}

__device__ __forceinline__ float wave_max(float v) {
    #pragma unroll
    for (int off = 32; off > 0; off >>= 1) v = fmaxf(v, __shfl_xor(v, off));
    return v;
}
__device__ __forceinline__ float wave_sum(float v) {
    #pragma unroll
    for (int off = 32; off > 0; off >>= 1) v += __shfl_xor(v, off);
    return v;
}

__global__ __launch_bounds__(256) void attn_partial_kernel(
    const float* __restrict__ Qw, const float* __restrict__ Kc,
    const float* __restrict__ Vc, const float* __restrict__ Kn,
    const float* __restrict__ Vn, float* __restrict__ part) {
    __shared__ float q_s[S_ * D_];
    __shared__ float ps[CS][4];
    __shared__ float ob[4][256];
    __shared__ float wred[4][4];
    __shared__ float msh[4], lsh[4];

    const int bh = blockIdx.x;
    const int c = blockIdx.y;
    const int tid = threadIdx.x;
    const int lane = tid & 63, wid = tid >> 6;

    q_s[tid] = Qw[(size_t)bh * 256 + tid];
    __syncthreads();

    const float* kptr;
    const float* vptr;
    int nrows;
    if (c < 8) {
        kptr = Kc + ((size_t)bh * KV_ + c * CS) * D_;
        vptr = Vc + ((size_t)bh * KV_ + c * CS) * D_;
        nrows = CS;
    } else {
        kptr = Kn + (size_t)bh * 256;
        vptr = Vn + (size_t)bh * 256;
        nrows = S_;
    }

    const float4* q4 = (const float4*)q_s;
    const float NEG = -1e30f;
    float4 sA = make_float4(NEG, NEG, NEG, NEG);
    float4 sB = make_float4(NEG, NEG, NEG, NEG);
    if (tid < nrows) sA = score4(q4, kptr, tid);
    if (256 + tid < nrows) sB = score4(q4, kptr, 256 + tid);

    // block max per query
    float4 tm;
    tm.x = wave_max(fmaxf(sA.x, sB.x));
    tm.y = wave_max(fmaxf(sA.y, sB.y));
    tm.z = wave_max(fmaxf(sA.z, sB.z));
    tm.w = wave_max(fmaxf(sA.w, sB.w));
    if (lane == 0) {
        wred[0][wid] = tm.x; wred[1][wid] = tm.y;
        wred[2][wid] = tm.z; wred[3][wid] = tm.w;
    }
    __syncthreads();
    if (tid < 4) {
        msh[tid] = fmaxf(fmaxf(wred[tid][0], wred[tid][1]),
                         fmaxf(wred[tid][2], wred[tid][3]));
    }
    __syncthreads();
    const float m0 = msh[0], m1 = msh[1], m2 = msh[2], m3 = msh[3];

    float4 tl = make_float4(0.f, 0.f, 0.f, 0.f);
    if (tid < nrows) {
        float4 p;
        p.x = __expf(sA.x - m0); p.y = __expf(sA.y - m1);
        p.z = __expf(sA.z - m2); p.w = __expf(sA.w - m3);
        *(float4*)ps[tid] = p;
        tl.x += p.x; tl.y += p.y; tl.z += p.z; tl.w += p.w;
    }
    if (256 + tid < nrows) {
        float4 p;
        p.x = __expf(sB.x - m0); p.y = __expf(sB.y - m1);
        p.z = __expf(sB.z - m2); p.w = __expf(sB.w - m3);
        *(float4*)ps[256 + tid] = p;
        tl.x += p.x; tl.y += p.y; tl.z += p.z; tl.w += p.w;
    }
    tl.x = wave_sum(tl.x);
    tl.y = wave_sum(tl.y);
    tl.z = wave_sum(tl.z);
    tl.w = wave_sum(tl.w);
    if (lane == 0) {
        wred[0][wid] = tl.x; wred[1][wid] = tl.y;
        wred[2][wid] = tl.z; wred[3][wid] = tl.w;
    }
    __syncthreads();
    if (tid < 4) {
        lsh[tid] = wred[tid][0] + wred[tid][1] + wred[tid][2] + wred[tid][3];
    }
    __syncthreads();   // also guarantees all ps[] writes are visible

    // Phase B: lane = head-dim, waves stride over rows
    float o0 = 0.f, o1 = 0.f, o2 = 0.f, o3 = 0.f;
    for (int r = wid; r < nrows; r += 4) {
        float4 p = *(const float4*)ps[r];           // broadcast within wave
        float v = vptr[(size_t)r * D_ + lane];      // coalesced 256B row read
        o0 = fmaf(p.x, v, o0);
        o1 = fmaf(p.y, v, o1);
        o2 = fmaf(p.z, v, o2);
        o3 = fmaf(p.w, v, o3);
    }
    ob[wid][0 * 64 + lane] = o0;
    ob[wid][1 * 64 + lane] = o1;
    ob[wid][2 * 64 + lane] = o2;
    ob[wid][3 * 64 + lane] = o3;
    __syncthreads();

    float* rec = part + ((size_t)bh * NC + c) * RECSZ;
    if (tid < 4) {
        rec[tid] = msh[tid];
        rec[4 + tid] = lsh[tid];
    }
    rec[8 + tid] = ob[0][tid] + ob[1][tid] + ob[2][tid] + ob[3][tid];
}

// ---------------------------------------------------------------------------
// Combine partials: out attn in [B,S,E] layout
// ---------------------------------------------------------------------------
__global__ __launch_bounds__(256) void attn_combine_kernel(
    const float* __restrict__ part, float* __restrict__ attn_out) {
    const int bh = blockIdx.x;
    const int tid = threadIdx.x;
    const int q = tid >> 6, dl = tid & 63;
    const float* base = part + (size_t)bh * NC * RECSZ;

    float m = -1e30f;
    #pragma unroll
    for (int c = 0; c < NC; ++c) m = fmaxf(m, base[c * RECSZ + q]);
    float l = 0.f, o = 0.f;
    #pragma unroll
    for (int c = 0; c < NC; ++c) {
        float w = __expf(base[c * RECSZ + q] - m);
        l = fmaf(base[c * RECSZ + 4 + q], w, l);
        o = fmaf(base[c * RECSZ + 8 + tid], w, o);
    }
    const float res = o / l;
    const int b = bh >> 4, h = bh & 15;
    attn_out[((size_t)(b * S_ + q)) * E_ + h * D_ + dl] = res;
}

// ---------------------------------------------------------------------------
extern "C" void kernel_launch(void* const* d_in, const int* in_sizes, int n_in,
                              void* d_out, int out_size, void* d_ws, size_t ws_size,
                              hipStream_t stream) {
    const float* x  = (const float*)d_in[0];
    const float* ck = (const float*)d_in[1];
    const float* cv = (const float*)d_in[2];
    const float* Wq = (const float*)d_in[3];
    const float* bq = (const float*)d_in[4];
    const float* Wk = (const float*)d_in[5];
    const float* bk = (const float*)d_in[6];
    const float* Wv = (const float*)d_in[7];
    const float* bv = (const float*)d_in[8];
    const float* Wo = (const float*)d_in[9];
    const float* bo = (const float*)d_in[10];
    float* out = (float*)d_out;
    float* ws = (float*)d_ws;

    float* Qw = ws;                       // 131072 floats
    float* Kn = ws + 131072;              // 131072
    float* Vn = ws + 262144;              // 131072
    float* part = ws + 393216;            // 512*9*264 = 1216512
    float* attn_out = ws + 393216 + 1216512;  // 131072

    dim3 pg(32, 16), pb(256);
    hipLaunchKernelGGL(proj_kernel, pg, pb, 0, stream, x, Wq, bq, Qw, 0);
    hipLaunchKernelGGL(proj_kernel, pg, pb, 0, stream, x, Wk, bk, Kn, 0);
    hipLaunchKernelGGL(proj_kernel, pg, pb, 0, stream, x, Wv, bv, Vn, 0);
    hipLaunchKernelGGL(attn_partial_kernel, dim3(NBH, NC), dim3(256), 0, stream,
                       Qw, ck, cv, Kn, Vn, part);
    hipLaunchKernelGGL(attn_combine_kernel, dim3(NBH), dim3(256), 0, stream,
                       part, attn_out);
    hipLaunchKernelGGL(proj_kernel, pg, pb, 0, stream, attn_out, Wo, bo, out, 1);
}

// Round 2
// 244.785 us; speedup vs baseline: 2.2036x; 2.2036x over previous
//
#include <hip/hip_runtime.h>
#include <math.h>

#define B_   32
#define S_   4
#define H_   16
#define D_   64
#define E_   1024
#define KV_  4096
#define NBH  512            // B_*H_
#define CS   512            // cached rows per chunk
#define NC   9              // 8 cache chunks + 1 "new rows" chunk
#define RECSZ 264           // 4 m + 4 l + 256 O floats per partial record

// ---------------------------------------------------------------------------
// Small GEMM: out = A[128,1024] @ W[1024,1024]^T + bias
// Cooperative 16-lane-per-row reads: every wave load is 4x256B segments
// (16 cache lines), fully coalesced.
// mode 0: scatter to [b,h,s,d];  mode 1: linear [t][e]
// grid (32, 16), block 256
// ---------------------------------------------------------------------------
__global__ __launch_bounds__(256) void proj_kernel(
    const float* __restrict__ A, const float* __restrict__ W,
    const float* __restrict__ bias, float* __restrict__ out, int mode) {
    __shared__ float a_lds[4 * E_];
    __shared__ float res[256];
    const int t0 = blockIdx.x * 4;
    const int n0 = blockIdx.y * 64;
    const int tid = threadIdx.x;
    const int lane = tid & 63, wid = tid >> 6;
    const int sub = lane >> 4, cg = lane & 15, tsel = cg & 3;

    const float4* Ag = (const float4*)(A + (size_t)t0 * E_);
    float4* al = (float4*)a_lds;
    #pragma unroll
    for (int i = 0; i < 4; ++i) al[tid + 256 * i] = Ag[tid + 256 * i];
    __syncthreads();

    #pragma unroll
    for (int g = 0; g < 4; ++g) {
        const int r0 = n0 + wid * 16 + g * 4;       // 4 W-rows for this wave
        const float4* wrow = (const float4*)(W + (size_t)r0 * E_);
        float ac0 = 0.f, ac1 = 0.f, ac2 = 0.f, ac3 = 0.f;
        #pragma unroll
        for (int kk = 0; kk < 16; ++kk) {
            float4 w4 = wrow[sub * 256 + kk * 16 + cg];
            float4 a0 = *(const float4*)&a_lds[0 * E_ + kk * 64 + cg * 4];
            float4 a1 = *(const float4*)&a_lds[1 * E_ + kk * 64 + cg * 4];
            float4 a2 = *(const float4*)&a_lds[2 * E_ + kk * 64 + cg * 4];
            float4 a3 = *(const float4*)&a_lds[3 * E_ + kk * 64 + cg * 4];
            ac0 += w4.x * a0.x + w4.y * a0.y + w4.z * a0.z + w4.w * a0.w;
            ac1 += w4.x * a1.x + w4.y * a1.y + w4.z * a1.z + w4.w * a1.w;
            ac2 += w4.x * a2.x + w4.y * a2.y + w4.z * a2.z + w4.w * a2.w;
            ac3 += w4.x * a3.x + w4.y * a3.y + w4.z * a3.z + w4.w * a3.w;
        }
        // reduce over 16 lanes: 2 rounds on all 4, select token, 2 rounds
        ac0 += __shfl_xor(ac0, 1); ac0 += __shfl_xor(ac0, 2);
        ac1 += __shfl_xor(ac1, 1); ac1 += __shfl_xor(ac1, 2);
        ac2 += __shfl_xor(ac2, 1); ac2 += __shfl_xor(ac2, 2);
        ac3 += __shfl_xor(ac3, 1); ac3 += __shfl_xor(ac3, 2);
        float v = (tsel & 1) ? ((tsel & 2) ? ac3 : ac1)
                             : ((tsel & 2) ? ac2 : ac0);
        v += __shfl_xor(v, 4); v += __shfl_xor(v, 8);
        if (cg < 4) res[cg * 64 + (wid * 16 + g * 4 + sub)] = v;
    }
    __syncthreads();

    const float val = res[tid] + bias[n0 + (tid & 63)];
    const int t = t0 + (tid >> 6), e = n0 + (tid & 63);
    if (mode == 0) {
        const int b = t >> 2, s = t & 3, h = e >> 6, dk = e & 63;
        out[((size_t)((b * H_ + h) * S_ + s)) * D_ + dk] = val;
    } else {
        out[(size_t)t * E_ + e] = val;
    }
}

// ---------------------------------------------------------------------------
// Attention partials (flash-decoding), fully coalesced 1KB wave loads
// ---------------------------------------------------------------------------
__device__ __forceinline__ float wave_sum(float v) {
    #pragma unroll
    for (int off = 32; off > 0; off >>= 1) v += __shfl_xor(v, off);
    return v;
}

__global__ __launch_bounds__(256) void attn_partial_kernel(
    const float* __restrict__ Qw, const float* __restrict__ Kc,
    const float* __restrict__ Vc, const float* __restrict__ Kn,
    const float* __restrict__ Vn, float* __restrict__ part) {
    __shared__ float q_s[S_ * D_];
    __shared__ float ps[CS][4];
    __shared__ float ob[4][256];
    __shared__ float wred[4][4];
    __shared__ float msh[4], lsh[4];

    const int bh = blockIdx.x;
    const int c = blockIdx.y;
    const int tid = threadIdx.x;
    const int lane = tid & 63, wid = tid >> 6;
    const int sub = lane >> 4, cg = lane & 15, qsel = cg & 3;

    q_s[tid] = Qw[(size_t)bh * 256 + tid];
    __syncthreads();

    const float* kptr;
    const float* vptr;
    int nrows;
    if (c < 8) {
        kptr = Kc + ((size_t)bh * KV_ + c * CS) * D_;
        vptr = Vc + ((size_t)bh * KV_ + c * CS) * D_;
        nrows = CS;
    } else {
        kptr = Kn + (size_t)bh * 256;
        vptr = Vn + (size_t)bh * 256;
        nrows = S_;
    }

    // per-lane Q fragments: query q, dims cg*4 .. cg*4+3
    const float4 q0 = *(const float4*)&q_s[0 * 64 + cg * 4];
    const float4 q1 = *(const float4*)&q_s[1 * 64 + cg * 4];
    const float4 q2 = *(const float4*)&q_s[2 * 64 + cg * 4];
    const float4 q3 = *(const float4*)&q_s[3 * 64 + cg * 4];

    // ---- score phase: wave load = 4 consecutive K rows (1KB contiguous) ----
    float mrun = -1e30f;
    for (int r0 = wid * 4; r0 < nrows; r0 += 16) {
        float4 kv = ((const float4*)(kptr + (size_t)r0 * D_))[lane];
        float p0 = kv.x * q0.x + kv.y * q0.y + kv.z * q0.z + kv.w * q0.w;
        float p1 = kv.x * q1.x + kv.y * q1.y + kv.z * q1.z + kv.w * q1.w;
        float p2 = kv.x * q2.x + kv.y * q2.y + kv.z * q2.z + kv.w * q2.w;
        float p3 = kv.x * q3.x + kv.y * q3.y + kv.z * q3.z + kv.w * q3.w;
        p0 += __shfl_xor(p0, 1); p0 += __shfl_xor(p0, 2);
        p1 += __shfl_xor(p1, 1); p1 += __shfl_xor(p1, 2);
        p2 += __shfl_xor(p2, 1); p2 += __shfl_xor(p2, 2);
        p3 += __shfl_xor(p3, 1); p3 += __shfl_xor(p3, 2);
        float v = (qsel & 1) ? ((qsel & 2) ? p3 : p1)
                             : ((qsel & 2) ? p2 : p0);
        v += __shfl_xor(v, 4); v += __shfl_xor(v, 8);
        v *= 0.125f;                                 // 1/sqrt(64)
        mrun = fmaxf(mrun, v);
        if (cg < 4) ps[r0 + sub][cg] = v;
    }
    // wave max over its rows (sub dimension), then block max
    mrun = fmaxf(mrun, __shfl_xor(mrun, 16));
    mrun = fmaxf(mrun, __shfl_xor(mrun, 32));
    if (lane < 4) wred[lane][wid] = mrun;
    __syncthreads();
    if (tid < 4) {
        msh[tid] = fmaxf(fmaxf(wred[tid][0], wred[tid][1]),
                         fmaxf(wred[tid][2], wred[tid][3]));
    }
    __syncthreads();
    const float m0 = msh[0], m1 = msh[1], m2 = msh[2], m3 = msh[3];

    // ---- exp pass: ps -> exp(ps - m), accumulate l ----
    float4 tl = make_float4(0.f, 0.f, 0.f, 0.f);
    for (int r = tid; r < nrows; r += 256) {
        float4 s = *(float4*)ps[r];
        s.x = __expf(s.x - m0); s.y = __expf(s.y - m1);
        s.z = __expf(s.z - m2); s.w = __expf(s.w - m3);
        *(float4*)ps[r] = s;
        tl.x += s.x; tl.y += s.y; tl.z += s.z; tl.w += s.w;
    }
    tl.x = wave_sum(tl.x); tl.y = wave_sum(tl.y);
    tl.z = wave_sum(tl.z); tl.w = wave_sum(tl.w);
    if (lane == 0) {
        wred[0][wid] = tl.x; wred[1][wid] = tl.y;
        wred[2][wid] = tl.z; wred[3][wid] = tl.w;
    }
    __syncthreads();
    if (tid < 4) {
        lsh[tid] = wred[tid][0] + wred[tid][1] + wred[tid][2] + wred[tid][3];
    }
    __syncthreads();   // ps[] fully exp'd and visible

    // ---- phase B: wave load = 4 consecutive V rows (1KB contiguous) ----
    float4 a0 = make_float4(0.f, 0.f, 0.f, 0.f);
    float4 a1 = a0, a2 = a0, a3 = a0;
    for (int r0 = wid * 4; r0 < nrows; r0 += 16) {
        float4 vv = ((const float4*)(vptr + (size_t)r0 * D_))[lane];
        float4 p = *(const float4*)ps[r0 + sub];     // this lane's row weights
        a0.x = fmaf(p.x, vv.x, a0.x); a0.y = fmaf(p.x, vv.y, a0.y);
        a0.z = fmaf(p.x, vv.z, a0.z); a0.w = fmaf(p.x, vv.w, a0.w);
        a1.x = fmaf(p.y, vv.x, a1.x); a1.y = fmaf(p.y, vv.y, a1.y);
        a1.z = fmaf(p.y, vv.z, a1.z); a1.w = fmaf(p.y, vv.w, a1.w);
        a2.x = fmaf(p.z, vv.x, a2.x); a2.y = fmaf(p.z, vv.y, a2.y);
        a2.z = fmaf(p.z, vv.z, a2.z); a2.w = fmaf(p.z, vv.w, a2.w);
        a3.x = fmaf(p.w, vv.x, a3.x); a3.y = fmaf(p.w, vv.y, a3.y);
        a3.z = fmaf(p.w, vv.z, a3.z); a3.w = fmaf(p.w, vv.w, a3.w);
    }
    // sum the 4 sub-groups (same dims, different rows)
    a0.x += __shfl_xor(a0.x, 16); a0.x += __shfl_xor(a0.x, 32);
    a0.y += __shfl_xor(a0.y, 16); a0.y += __shfl_xor(a0.y, 32);
    a0.z += __shfl_xor(a0.z, 16); a0.z += __shfl_xor(a0.z, 32);
    a0.w += __shfl_xor(a0.w, 16); a0.w += __shfl_xor(a0.w, 32);
    a1.x += __shfl_xor(a1.x, 16); a1.x += __shfl_xor(a1.x, 32);
    a1.y += __shfl_xor(a1.y, 16); a1.y += __shfl_xor(a1.y, 32);
    a1.z += __shfl_xor(a1.z, 16); a1.z += __shfl_xor(a1.z, 32);
    a1.w += __shfl_xor(a1.w, 16); a1.w += __shfl_xor(a1.w, 32);
    a2.x += __shfl_xor(a2.x, 16); a2.x += __shfl_xor(a2.x, 32);
    a2.y += __shfl_xor(a2.y, 16); a2.y += __shfl_xor(a2.y, 32);
    a2.z += __shfl_xor(a2.z, 16); a2.z += __shfl_xor(a2.z, 32);
    a2.w += __shfl_xor(a2.w, 16); a2.w += __shfl_xor(a2.w, 32);
    a3.x += __shfl_xor(a3.x, 16); a3.x += __shfl_xor(a3.x, 32);
    a3.y += __shfl_xor(a3.y, 16); a3.y += __shfl_xor(a3.y, 32);
    a3.z += __shfl_xor(a3.z, 16); a3.z += __shfl_xor(a3.z, 32);
    a3.w += __shfl_xor(a3.w, 16); a3.w += __shfl_xor(a3.w, 32);
    if (sub == 0) {
        *(float4*)&ob[wid][0 * 64 + cg * 4] = a0;
        *(float4*)&ob[wid][1 * 64 + cg * 4] = a1;
        *(float4*)&ob[wid][2 * 64 + cg * 4] = a2;
        *(float4*)&ob[wid][3 * 64 + cg * 4] = a3;
    }
    __syncthreads();

    float* rec = part + ((size_t)bh * NC + c) * RECSZ;
    if (tid < 4) {
        rec[tid] = msh[tid];
        rec[4 + tid] = lsh[tid];
    }
    rec[8 + tid] = ob[0][tid] + ob[1][tid] + ob[2][tid] + ob[3][tid];
}

// ---------------------------------------------------------------------------
// Combine partials: attn output in [B,S,E] layout
// ---------------------------------------------------------------------------
__global__ __launch_bounds__(256) void attn_combine_kernel(
    const float* __restrict__ part, float* __restrict__ attn_out) {
    const int bh = blockIdx.x;
    const int tid = threadIdx.x;
    const int q = tid >> 6, dl = tid & 63;
    const float* base = part + (size_t)bh * NC * RECSZ;

    float m = -1e30f;
    #pragma unroll
    for (int c = 0; c < NC; ++c) m = fmaxf(m, base[c * RECSZ + q]);
    float l = 0.f, o = 0.f;
    #pragma unroll
    for (int c = 0; c < NC; ++c) {
        float w = __expf(base[c * RECSZ + q] - m);
        l = fmaf(base[c * RECSZ + 4 + q], w, l);
        o = fmaf(base[c * RECSZ + 8 + tid], w, o);
    }
    const float res = o / l;
    const int b = bh >> 4, h = bh & 15;
    attn_out[((size_t)(b * S_ + q)) * E_ + h * D_ + dl] = res;
}

// ---------------------------------------------------------------------------
extern "C" void kernel_launch(void* const* d_in, const int* in_sizes, int n_in,
                              void* d_out, int out_size, void* d_ws, size_t ws_size,
                              hipStream_t stream) {
    const float* x  = (const float*)d_in[0];
    const float* ck = (const float*)d_in[1];
    const float* cv = (const float*)d_in[2];
    const float* Wq = (const float*)d_in[3];
    const float* bq = (const float*)d_in[4];
    const float* Wk = (const float*)d_in[5];
    const float* bk = (const float*)d_in[6];
    const float* Wv = (const float*)d_in[7];
    const float* bv = (const float*)d_in[8];
    const float* Wo = (const float*)d_in[9];
    const float* bo = (const float*)d_in[10];
    float* out = (float*)d_out;
    float* ws = (float*)d_ws;

    float* Qw = ws;                       // 131072 floats
    float* Kn = ws + 131072;              // 131072
    float* Vn = ws + 262144;              // 131072
    float* part = ws + 393216;            // 512*9*264 = 1216512
    float* attn_out = ws + 393216 + 1216512;  // 131072

    dim3 pg(32, 16), pb(256);
    hipLaunchKernelGGL(proj_kernel, pg, pb, 0, stream, x, Wq, bq, Qw, 0);
    hipLaunchKernelGGL(proj_kernel, pg, pb, 0, stream, x, Wk, bk, Kn, 0);
    hipLaunchKernelGGL(proj_kernel, pg, pb, 0, stream, x, Wv, bv, Vn, 0);
    hipLaunchKernelGGL(attn_partial_kernel, dim3(NBH, NC), dim3(256), 0, stream,
                       Qw, ck, cv, Kn, Vn, part);
    hipLaunchKernelGGL(attn_combine_kernel, dim3(NBH), dim3(256), 0, stream,
                       part, attn_out);
    hipLaunchKernelGGL(proj_kernel, pg, pb, 0, stream, attn_out, Wo, bo, out, 1);
}